// Round 1
// 1026.780 us; speedup vs baseline: 1.0463x; 1.0463x over previous
//
#include <hip/hip_runtime.h>
#include <stdint.h>

#define S_LEN 200
#define BATCH 1024
#define HID   128
#define VOCAB 100000

typedef __attribute__((ext_vector_type(4))) float f32x4;
typedef __attribute__((ext_vector_type(8))) short bf16x8;

__device__ __forceinline__ unsigned short f2bf(float f) {
  union { float f; uint32_t u; } v; v.f = f;
  uint32_t u = v.u;
  uint32_t r = u + 0x7fffu + ((u >> 16) & 1u);   // RNE
  return (unsigned short)(r >> 16);
}

// ---------------------------------------------------------------------------
// K0: Wfc f32 -> bf16 (one pass, 154 MB streamed). Lets K3 read half the
// bytes and drop the per-thread f2bf chains.
// ---------------------------------------------------------------------------
__global__ __launch_bounds__(256) void k0_wfc_bf16(
    const float* __restrict__ Wfc, unsigned short* __restrict__ Wfcb) {
  size_t i = ((size_t)blockIdx.x * 256 + threadIdx.x) * 8;   // 12500*256*8 = 25.6M
  f32x4 a = *(const f32x4*)&Wfc[i];
  f32x4 b = *(const f32x4*)&Wfc[i + 4];
  uint4 pk;
  pk.x = (uint32_t)f2bf(a.x) | ((uint32_t)f2bf(a.y) << 16);
  pk.y = (uint32_t)f2bf(a.z) | ((uint32_t)f2bf(a.w) << 16);
  pk.z = (uint32_t)f2bf(b.x) | ((uint32_t)f2bf(b.y) << 16);
  pk.w = (uint32_t)f2bf(b.z) | ((uint32_t)f2bf(b.w) << 16);
  *(uint4*)&Wfcb[i] = pk;
}

// ---------------------------------------------------------------------------
// K1: E[v][j] = sum_k Wenc[v][k]*Wih[j][k] + bih[j] + bhh[j]
// fp32 vector GEMM, 64v x 128j block tile, 4v x 8j thread tile (interleaved)
// ---------------------------------------------------------------------------
__global__ __launch_bounds__(256) void k1_eprecomp(
    const float* __restrict__ Wenc, const float* __restrict__ Wih,
    const float* __restrict__ bih, const float* __restrict__ bhh,
    float* __restrict__ E) {
  __shared__ float Wlds[128][132];
  __shared__ float Alds[64][132];
  const int tid = threadIdx.x;
  const int v0 = blockIdx.x * 64;

  #pragma unroll
  for (int i = 0; i < 16; ++i) {                 // Wih 128x128 -> LDS
    int g = tid + i * 256;                        // float4 index
    int row = g >> 5, c4 = g & 31;
    *(f32x4*)&Wlds[row][c4 * 4] = *(const f32x4*)&Wih[row * 128 + c4 * 4];
  }
  #pragma unroll
  for (int i = 0; i < 8; ++i) {                  // Wenc tile 64x128 -> LDS
    int g = tid + i * 256;
    int row = g >> 5, c4 = g & 31;
    int v = v0 + row;
    *(f32x4*)&Alds[row][c4 * 4] =
        *(const f32x4*)&Wenc[(size_t)(v < VOCAB ? v : 0) * 128 + c4 * 4];
  }
  __syncthreads();

  const int jt = tid & 15, vt = tid >> 4;
  float acc[4][8];
  #pragma unroll
  for (int a = 0; a < 4; ++a)
    #pragma unroll
    for (int b = 0; b < 8; ++b) acc[a][b] = 0.f;

  for (int kk = 0; kk < 32; ++kk) {
    f32x4 av[4], wv[8];
    #pragma unroll
    for (int vv = 0; vv < 4; ++vv) av[vv] = *(const f32x4*)&Alds[vt + 16 * vv][kk * 4];
    #pragma unroll
    for (int jj = 0; jj < 8; ++jj) wv[jj] = *(const f32x4*)&Wlds[jt + 16 * jj][kk * 4];
    #pragma unroll
    for (int vv = 0; vv < 4; ++vv)
      #pragma unroll
      for (int jj = 0; jj < 8; ++jj)
        acc[vv][jj] += av[vv].x * wv[jj].x + av[vv].y * wv[jj].y +
                       av[vv].z * wv[jj].z + av[vv].w * wv[jj].w;
  }

  #pragma unroll
  for (int jj = 0; jj < 8; ++jj) {
    int j = jt + 16 * jj;
    float bias = bih[j] + bhh[j];
    #pragma unroll
    for (int vv = 0; vv < 4; ++vv) {
      int v = v0 + vt + 16 * vv;
      if (v < VOCAB) E[(size_t)v * 128 + j] = acc[vv][jj] + bias;
    }
  }
}

// ---------------------------------------------------------------------------
// K1b: pooling weights w[t,b]
// ---------------------------------------------------------------------------
__global__ __launch_bounds__(256) void k1b_weights(
    const float* __restrict__ t, const float* __restrict__ s,
    const int* __restrict__ length, float* __restrict__ wbuf) {
  int idx = blockIdx.x * 256 + threadIdx.x;      // S*B = 204800
  int ts = idx >> 10, b = idx & 1023;
  int len = length[b];
  float w = 0.f;
  if (ts < len) {
    int last = len - 1;
    float tl  = t[last * BATCH + b];
    float slx = s[(last * BATCH + b) * 2 + 0];
    float sly = s[(last * BATCH + b) * 2 + 1];
    float dt = tl - t[ts * BATCH + b];
    float dx = slx - s[(ts * BATCH + b) * 2 + 0];
    float dy = sly - s[(ts * BATCH + b) * 2 + 1];
    float ds = sqrtf(dx * dx + dy * dy);
    float ft = (__cosf(dt * 7.2722052166430399e-05f) + 1.f) * 0.5f *
               __expf(dt * -1.1574074074074073e-06f);
    float fs = __expf(-1000.f * ds);
    w = ft * fs + 1e-10f;
  }
  wbuf[idx] = w;
}

// ---------------------------------------------------------------------------
// K2: RNN over 200 steps + fused online pooling.
// 512 blocks x 256 thr; block owns 2 batch rows. Thread = (j = wave*32+lane/2,
// kh = lane&1) holds W_hh[j][kh*64..+64) in registers. h broadcast from LDS.
// A is written as bf16 (bit-identical to the f2bf K3 used to apply).
// ---------------------------------------------------------------------------
__global__ __launch_bounds__(256) void k2_rnn(
    const int* __restrict__ x, const float* __restrict__ E,
    const float* __restrict__ Whh, const float* __restrict__ h0,
    const float* __restrict__ wbuf,
    const int* __restrict__ active_user, const float* __restrict__ Wuser,
    unsigned short* __restrict__ A) {
  __shared__ float hlds[2][2][128];
  const int tid = threadIdx.x;
  const int lane = tid & 63, wv = tid >> 6;
  const int j = wv * 32 + (lane >> 1);
  const int kh = lane & 1;
  const int b0 = blockIdx.x * 2, b1 = b0 + 1;

  f32x4 Wr[16];
  const float* wrow = &Whh[j * 128 + kh * 64];
  #pragma unroll
  for (int i = 0; i < 16; ++i) Wr[i] = *(const f32x4*)&wrow[i * 4];

  { int bb = tid >> 7, jj = tid & 127;
    hlds[0][bb][jj] = h0[(b0 + bb) * 128 + jj]; }
  __syncthreads();

  float acc0 = 0.f, acc1 = 0.f, ws0 = 0.f, ws1 = 0.f;
  int xc0 = x[b0], xc1 = x[b1];
  int xn0 = x[1024 + b0], xn1 = x[1024 + b1];
  float ec0 = E[(size_t)xc0 * 128 + j], ec1 = E[(size_t)xc1 * 128 + j];
  float wc0 = wbuf[b0], wc1 = wbuf[b1];

  for (int t = 0; t < S_LEN; ++t) {
    int rb = t & 1, wb = rb ^ 1;
    int xf0 = 0, xf1 = 0;
    float en0 = 0.f, en1 = 0.f, wn0 = 0.f, wn1 = 0.f;
    if (t + 2 < S_LEN) { xf0 = x[(t + 2) * 1024 + b0]; xf1 = x[(t + 2) * 1024 + b1]; }
    if (t + 1 < S_LEN) {
      en0 = E[(size_t)xn0 * 128 + j]; en1 = E[(size_t)xn1 * 128 + j];
      wn0 = wbuf[(t + 1) * 1024 + b0]; wn1 = wbuf[(t + 1) * 1024 + b1];
    }
    float p0 = 0.f, p1 = 0.f;
    const float* h0p = &hlds[rb][0][kh * 64];
    const float* h1p = &hlds[rb][1][kh * 64];
    #pragma unroll
    for (int i = 0; i < 16; ++i) {
      f32x4 hv0 = *(const f32x4*)&h0p[i * 4];
      f32x4 hv1 = *(const f32x4*)&h1p[i * 4];
      p0 += Wr[i].x * hv0.x + Wr[i].y * hv0.y + Wr[i].z * hv0.z + Wr[i].w * hv0.w;
      p1 += Wr[i].x * hv1.x + Wr[i].y * hv1.y + Wr[i].z * hv1.z + Wr[i].w * hv1.w;
    }
    p0 += __shfl_xor(p0, 1, 64);
    p1 += __shfl_xor(p1, 1, 64);
    float hn0 = tanhf(p0 + ec0);
    float hn1 = tanhf(p1 + ec1);
    acc0 += wc0 * hn0; ws0 += wc0;
    acc1 += wc1 * hn1; ws1 += wc1;
    if (kh == 0) { hlds[wb][0][j] = hn0; hlds[wb][1][j] = hn1; }
    __syncthreads();
    xc0 = xn0; xc1 = xn1; xn0 = xf0; xn1 = xf1;
    ec0 = en0; ec1 = en1; wc0 = wn0; wc1 = wn1;
  }

  if (kh == 0) {
    A[b0 * 256 + j] = f2bf(acc0 / ws0);
    A[b1 * 256 + j] = f2bf(acc1 / ws1);
    int u0 = active_user[b0], u1 = active_user[b1];
    A[b0 * 256 + 128 + j] = f2bf(Wuser[u0 * 128 + j]);
    A[b1 * 256 + 128 + j] = f2bf(Wuser[u1 * 128 + j]);
  }
}

// ---------------------------------------------------------------------------
// K3: out[b][v] = sum_k A[b][k]*Wfc[v][k] + bfc[v]   (bf16 MFMA, f32 accum)
// block tile 64m x 256n, wave tile 64x64, K=256 in 8 chunks of 32.
// - XCD-bijective block remap: all 16 m-blocks sharing a Wfc n-tile run
//   consecutively on ONE XCD (6256 = 8*782 exactly) -> tile fetched ~once.
// - A tile: bf16 in 32KB LDS with XOR swizzle (byte ^= (row&7)<<4) -> uniform
//   bank spread on both the 16B ds_writes and ds_reads; 5 blocks/CU.
// - PRE: Wfc pre-converted to bf16 (k0); else in-register f2bf fallback.
// ---------------------------------------------------------------------------
template <bool PRE>
__global__ __launch_bounds__(256) void k3_gemm(
    const unsigned short* __restrict__ Ab, const void* __restrict__ W,
    const float* __restrict__ bfc, float* __restrict__ out) {
  __shared__ unsigned short Alds[64 * 256];      // 32768 B
  const int tid = threadIdx.x;
  const int bid = blockIdx.x;
  // XCD swizzle: bid%8 = XCD (round-robin dispatch); give each XCD a
  // contiguous chunk of the (nblk, mblk) space. 6256/8 = 782 exact.
  const int linear = (bid & 7) * 782 + (bid >> 3);
  const int nblk = linear >> 4;        // 0..390
  const int mblk = linear & 15;
  const int m0 = mblk * 64;
  const int v0 = nblk * 256;

  #pragma unroll
  for (int i = 0; i < 8; ++i) {        // A 64x256 bf16 -> swizzled LDS
    int u = tid + i * 256;             // 16B unit index, 2048 total
    int row = u >> 5, cu = u & 31;
    uint32_t byte = (uint32_t)(row << 9) + (uint32_t)(cu << 4);
    byte ^= (uint32_t)((row & 7) << 4);
    uint4 val = *(const uint4*)&Ab[(size_t)(m0 + row) * 256 + cu * 8];
    *(uint4*)((char*)Alds + byte) = val;
  }
  __syncthreads();

  const int lane = tid & 63, wid = tid >> 6;
  const int lm = lane & 15, quad = lane >> 4;
  const int vbase = v0 + wid * 64;

  f32x4 acc[4][4];
  #pragma unroll
  for (int mt = 0; mt < 4; ++mt)
    #pragma unroll
    for (int nt = 0; nt < 4; ++nt) acc[mt][nt] = (f32x4){0.f, 0.f, 0.f, 0.f};

  const char* bbase[4];
  #pragma unroll
  for (int nt = 0; nt < 4; ++nt) {
    int v = vbase + nt * 16 + lm;
    size_t vc = (size_t)(v < VOCAB ? v : (VOCAB - 1));
    if constexpr (PRE)
      bbase[nt] = (const char*)((const unsigned short*)W + vc * 256);
    else
      bbase[nt] = (const char*)((const float*)W + vc * 256);
  }

  for (int kc = 0; kc < 8; ++kc) {
    const int k0 = kc * 32 + quad * 8;           // bf16 element index
    bf16x8 af[4], bfr[4];
    #pragma unroll
    for (int mt = 0; mt < 4; ++mt) {
      int row = mt * 16 + lm;
      uint32_t byte = (uint32_t)(row << 9) + (uint32_t)(k0 << 1);
      byte ^= (uint32_t)((row & 7) << 4);
      af[mt] = *(const bf16x8*)((const char*)Alds + byte);
    }
    #pragma unroll
    for (int nt = 0; nt < 4; ++nt) {
      if constexpr (PRE) {
        bfr[nt] = *(const bf16x8*)(bbase[nt] + (size_t)k0 * 2);
      } else {
        const float* bp = (const float*)bbase[nt];
        f32x4 w0 = *(const f32x4*)&bp[k0];
        f32x4 w1 = *(const f32x4*)&bp[k0 + 4];
        bf16x8 b;
        b[0] = (short)f2bf(w0.x); b[1] = (short)f2bf(w0.y);
        b[2] = (short)f2bf(w0.z); b[3] = (short)f2bf(w0.w);
        b[4] = (short)f2bf(w1.x); b[5] = (short)f2bf(w1.y);
        b[6] = (short)f2bf(w1.z); b[7] = (short)f2bf(w1.w);
        bfr[nt] = b;
      }
    }
    #pragma unroll
    for (int mt = 0; mt < 4; ++mt)
      #pragma unroll
      for (int nt = 0; nt < 4; ++nt)
        acc[mt][nt] = __builtin_amdgcn_mfma_f32_16x16x32_bf16(
            af[mt], bfr[nt], acc[mt][nt], 0, 0, 0);
  }

  #pragma unroll
  for (int nt = 0; nt < 4; ++nt) {
    int v = vbase + nt * 16 + lm;
    if (v >= VOCAB) continue;
    float bias = bfc[v];
    #pragma unroll
    for (int mt = 0; mt < 4; ++mt) {
      int row = m0 + mt * 16 + quad * 4;
      #pragma unroll
      for (int r = 0; r < 4; ++r)
        out[(size_t)(row + r) * VOCAB + v] = acc[mt][nt][r] + bias;
    }
  }
}

// ---------------------------------------------------------------------------
extern "C" void kernel_launch(void* const* d_in, const int* in_sizes, int n_in,
                              void* d_out, int out_size, void* d_ws, size_t ws_size,
                              hipStream_t stream) {
  const int*   x     = (const int*)d_in[0];
  const float* t     = (const float*)d_in[1];
  const float* s     = (const float*)d_in[2];
  // d_in[3] = y_t, d_in[4] = y_s  (unused by reference)
  const float* h0    = (const float*)d_in[5];
  const int*   au    = (const int*)d_in[6];
  const int*   len   = (const int*)d_in[7];
  const float* Wenc  = (const float*)d_in[8];
  const float* Wuser = (const float*)d_in[9];
  const float* Wih   = (const float*)d_in[10];
  const float* Whh   = (const float*)d_in[11];
  const float* bih   = (const float*)d_in[12];
  const float* bhh   = (const float*)d_in[13];
  const float* Wfc   = (const float*)d_in[14];
  const float* bfc   = (const float*)d_in[15];
  float* out = (float*)d_out;

  char* ws = (char*)d_ws;
  float*          E    = (float*)(ws);                    // 100000*128*4 = 51,200,000
  float*          wbuf = (float*)(ws + 51200000);         // 200*1024*4   =    819,200
  unsigned short* Ab   = (unsigned short*)(ws + 52019200);// 1024*256*2   =    524,288
  unsigned short* Wfcb = (unsigned short*)(ws + 52543488);// 100000*256*2 = 51,200,000
  const size_t need = 52543488ull + 51200000ull;          // 103,743,488
  const bool pre = ws_size >= need;

  if (pre) k0_wfc_bf16<<<12500, 256, 0, stream>>>(Wfc, Wfcb);
  k1_eprecomp<<<1563, 256, 0, stream>>>(Wenc, Wih, bih, bhh, E);
  k1b_weights<<<800, 256, 0, stream>>>(t, s, len, wbuf);
  k2_rnn<<<512, 256, 0, stream>>>(x, E, Whh, h0, wbuf, au, Wuser, Ab);
  if (pre)
    k3_gemm<true><<<6256, 256, 0, stream>>>(Ab, (const void*)Wfcb, bfc, out);
  else
    k3_gemm<false><<<6256, 256, 0, stream>>>(Ab, (const void*)Wfc, bfc, out);
}

// Round 2
// 927.596 us; speedup vs baseline: 1.1582x; 1.1069x over previous
//
#include <hip/hip_runtime.h>
#include <stdint.h>

#define S_LEN 200
#define BATCH 1024
#define HID   128
#define VOCAB 100000

typedef __attribute__((ext_vector_type(4))) float f32x4;
typedef __attribute__((ext_vector_type(8))) short bf16x8;

__device__ __forceinline__ unsigned short f2bf(float f) {
  union { float f; uint32_t u; } v; v.f = f;
  uint32_t u = v.u;
  uint32_t r = u + 0x7fffu + ((u >> 16) & 1u);   // RNE
  return (unsigned short)(r >> 16);
}

__device__ __forceinline__ float tanh_fast(float x) {
  // tanh(x) = 1 - 2/(exp(2x)+1); exact at +-inf, rel err ~1e-6 (v_exp_f32)
  float e = __expf(2.0f * x);
  return 1.0f - 2.0f / (e + 1.0f);
}

// ---------------------------------------------------------------------------
// K0: Wfc f32 -> bf16 (one pass, 154 MB streamed).
// ---------------------------------------------------------------------------
__global__ __launch_bounds__(256) void k0_wfc_bf16(
    const float* __restrict__ Wfc, unsigned short* __restrict__ Wfcb) {
  size_t i = ((size_t)blockIdx.x * 256 + threadIdx.x) * 8;   // 12500*256*8 = 25.6M
  f32x4 a = *(const f32x4*)&Wfc[i];
  f32x4 b = *(const f32x4*)&Wfc[i + 4];
  uint4 pk;
  pk.x = (uint32_t)f2bf(a.x) | ((uint32_t)f2bf(a.y) << 16);
  pk.y = (uint32_t)f2bf(a.z) | ((uint32_t)f2bf(a.w) << 16);
  pk.z = (uint32_t)f2bf(b.x) | ((uint32_t)f2bf(b.y) << 16);
  pk.w = (uint32_t)f2bf(b.z) | ((uint32_t)f2bf(b.w) << 16);
  *(uint4*)&Wfcb[i] = pk;
}

// ---------------------------------------------------------------------------
// K1: E[v][j] = sum_k Wenc[v][k]*Wih[j][k] + bih[j] + bhh[j]
// fp32 vector GEMM, 64v x 128j block tile, 4v x 8j thread tile (interleaved)
// ---------------------------------------------------------------------------
__global__ __launch_bounds__(256) void k1_eprecomp(
    const float* __restrict__ Wenc, const float* __restrict__ Wih,
    const float* __restrict__ bih, const float* __restrict__ bhh,
    float* __restrict__ E) {
  __shared__ float Wlds[128][132];
  __shared__ float Alds[64][132];
  const int tid = threadIdx.x;
  const int v0 = blockIdx.x * 64;

  #pragma unroll
  for (int i = 0; i < 16; ++i) {                 // Wih 128x128 -> LDS
    int g = tid + i * 256;                        // float4 index
    int row = g >> 5, c4 = g & 31;
    *(f32x4*)&Wlds[row][c4 * 4] = *(const f32x4*)&Wih[row * 128 + c4 * 4];
  }
  #pragma unroll
  for (int i = 0; i < 8; ++i) {                  // Wenc tile 64x128 -> LDS
    int g = tid + i * 256;
    int row = g >> 5, c4 = g & 31;
    int v = v0 + row;
    *(f32x4*)&Alds[row][c4 * 4] =
        *(const f32x4*)&Wenc[(size_t)(v < VOCAB ? v : 0) * 128 + c4 * 4];
  }
  __syncthreads();

  const int jt = tid & 15, vt = tid >> 4;
  float acc[4][8];
  #pragma unroll
  for (int a = 0; a < 4; ++a)
    #pragma unroll
    for (int b = 0; b < 8; ++b) acc[a][b] = 0.f;

  for (int kk = 0; kk < 32; ++kk) {
    f32x4 av[4], wv[8];
    #pragma unroll
    for (int vv = 0; vv < 4; ++vv) av[vv] = *(const f32x4*)&Alds[vt + 16 * vv][kk * 4];
    #pragma unroll
    for (int jj = 0; jj < 8; ++jj) wv[jj] = *(const f32x4*)&Wlds[jt + 16 * jj][kk * 4];
    #pragma unroll
    for (int vv = 0; vv < 4; ++vv)
      #pragma unroll
      for (int jj = 0; jj < 8; ++jj)
        acc[vv][jj] += av[vv].x * wv[jj].x + av[vv].y * wv[jj].y +
                       av[vv].z * wv[jj].z + av[vv].w * wv[jj].w;
  }

  #pragma unroll
  for (int jj = 0; jj < 8; ++jj) {
    int j = jt + 16 * jj;
    float bias = bih[j] + bhh[j];
    #pragma unroll
    for (int vv = 0; vv < 4; ++vv) {
      int v = v0 + vt + 16 * vv;
      if (v < VOCAB) E[(size_t)v * 128 + j] = acc[vv][jj] + bias;
    }
  }
}

// ---------------------------------------------------------------------------
// K1b: pooling weights w[t,b]
// ---------------------------------------------------------------------------
__global__ __launch_bounds__(256) void k1b_weights(
    const float* __restrict__ t, const float* __restrict__ s,
    const int* __restrict__ length, float* __restrict__ wbuf) {
  int idx = blockIdx.x * 256 + threadIdx.x;      // S*B = 204800
  int ts = idx >> 10, b = idx & 1023;
  int len = length[b];
  float w = 0.f;
  if (ts < len) {
    int last = len - 1;
    float tl  = t[last * BATCH + b];
    float slx = s[(last * BATCH + b) * 2 + 0];
    float sly = s[(last * BATCH + b) * 2 + 1];
    float dt = tl - t[ts * BATCH + b];
    float dx = slx - s[(ts * BATCH + b) * 2 + 0];
    float dy = sly - s[(ts * BATCH + b) * 2 + 1];
    float ds = sqrtf(dx * dx + dy * dy);
    float ft = (__cosf(dt * 7.2722052166430399e-05f) + 1.f) * 0.5f *
               __expf(dt * -1.1574074074074073e-06f);
    float fs = __expf(-1000.f * ds);
    w = ft * fs + 1e-10f;
  }
  wbuf[idx] = w;
}

// ---------------------------------------------------------------------------
// K2: RNN over 200 steps + fused online pooling.
// 1024 blocks x 256 thr; block owns ONE batch row (4 blocks/CU = 16 waves/CU).
// Thread = (j = wave*32+lane/2, kh = lane&1) holds W_hh[j][kh*64..+64) in
// registers. h broadcast from LDS with the kh=1 half padded to byte offset
// 288 (bank shift +8) -> the two half-wave addresses hit disjoint banks
// (kills the 5.2e7 SQ_LDS_BANK_CONFLICT of the previous layout).
// f32x4 accumulator = 4 independent FMA chains of 16 (was one 64-deep chain).
// ---------------------------------------------------------------------------
__global__ __launch_bounds__(256, 4) void k2_rnn(
    const int* __restrict__ x, const float* __restrict__ E,
    const float* __restrict__ Whh, const float* __restrict__ h0,
    const float* __restrict__ wbuf,
    const int* __restrict__ active_user, const float* __restrict__ Wuser,
    unsigned short* __restrict__ A) {
  // h[j] stored at index j + (j>=64 ? 8 : 0): halves at float-offset 0 and 72
  __shared__ float hlds[2][144];
  const int tid = threadIdx.x;
  const int lane = tid & 63, wv = tid >> 6;
  const int j = wv * 32 + (lane >> 1);
  const int kh = lane & 1;
  const int b = blockIdx.x;

  f32x4 Wr[16];
  const float* wrow = &Whh[j * 128 + kh * 64];
  #pragma unroll
  for (int i = 0; i < 16; ++i) Wr[i] = *(const f32x4*)&wrow[i * 4];

  if (tid < 128) hlds[0][tid + (tid >> 6) * 8] = h0[b * 128 + tid];
  __syncthreads();

  float acc = 0.f, ws = 0.f;
  int xc = x[b];
  int xn = x[1024 + b];
  float ec = E[(size_t)xc * 128 + j];
  float wc = wbuf[b];

  for (int t = 0; t < S_LEN; ++t) {
    int rb = t & 1, wb = rb ^ 1;
    int xf = 0;
    float en = 0.f, wn = 0.f;
    if (t + 2 < S_LEN) xf = x[(t + 2) * 1024 + b];
    if (t + 1 < S_LEN) {
      en = E[(size_t)xn * 128 + j];
      wn = wbuf[(t + 1) * 1024 + b];
    }
    const float* hp = &hlds[rb][kh * 72];
    f32x4 a4 = (f32x4){0.f, 0.f, 0.f, 0.f};
    #pragma unroll
    for (int i = 0; i < 16; ++i) {
      f32x4 hv = *(const f32x4*)&hp[i * 4];
      a4 += Wr[i] * hv;
    }
    float p = (a4.x + a4.y) + (a4.z + a4.w);
    p += __shfl_xor(p, 1, 64);
    float hn = tanh_fast(p + ec);
    acc += wc * hn; ws += wc;
    if (kh == 0) hlds[wb][j + (j >> 6) * 8] = hn;
    __syncthreads();
    xc = xn; xn = xf; ec = en; wc = wn;
  }

  if (kh == 0) {
    A[b * 256 + j] = f2bf(acc / ws);
    int u = active_user[b];
    A[b * 256 + 128 + j] = f2bf(Wuser[u * 128 + j]);
  }
}

// ---------------------------------------------------------------------------
// K3: out[b][v] = sum_k A[b][k]*Wfc[v][k] + bfc[v]   (bf16 MFMA, f32 accum)
// block tile 64m x 256n, wave tile 64x64, K=256 in 8 chunks of 32.
// - XCD-bijective block remap: all 16 m-blocks sharing a Wfc n-tile run
//   consecutively on ONE XCD (6256 = 8*782 exactly) -> tile fetched ~once.
// - A tile: bf16 in 32KB LDS with XOR swizzle (byte ^= (row&7)<<4) -> uniform
//   bank spread on both the 16B ds_writes and ds_reads; 5 blocks/CU.
// - PRE: Wfc pre-converted to bf16 (k0); else in-register f2bf fallback.
// ---------------------------------------------------------------------------
template <bool PRE>
__global__ __launch_bounds__(256) void k3_gemm(
    const unsigned short* __restrict__ Ab, const void* __restrict__ W,
    const float* __restrict__ bfc, float* __restrict__ out) {
  __shared__ unsigned short Alds[64 * 256];      // 32768 B
  const int tid = threadIdx.x;
  const int bid = blockIdx.x;
  const int linear = (bid & 7) * 782 + (bid >> 3);
  const int nblk = linear >> 4;        // 0..390
  const int mblk = linear & 15;
  const int m0 = mblk * 64;
  const int v0 = nblk * 256;

  #pragma unroll
  for (int i = 0; i < 8; ++i) {        // A 64x256 bf16 -> swizzled LDS
    int u = tid + i * 256;             // 16B unit index, 2048 total
    int row = u >> 5, cu = u & 31;
    uint32_t byte = (uint32_t)(row << 9) + (uint32_t)(cu << 4);
    byte ^= (uint32_t)((row & 7) << 4);
    uint4 val = *(const uint4*)&Ab[(size_t)(m0 + row) * 256 + cu * 8];
    *(uint4*)((char*)Alds + byte) = val;
  }
  __syncthreads();

  const int lane = tid & 63, wid = tid >> 6;
  const int lm = lane & 15, quad = lane >> 4;
  const int vbase = v0 + wid * 64;

  f32x4 acc[4][4];
  #pragma unroll
  for (int mt = 0; mt < 4; ++mt)
    #pragma unroll
    for (int nt = 0; nt < 4; ++nt) acc[mt][nt] = (f32x4){0.f, 0.f, 0.f, 0.f};

  const char* bbase[4];
  #pragma unroll
  for (int nt = 0; nt < 4; ++nt) {
    int v = vbase + nt * 16 + lm;
    size_t vc = (size_t)(v < VOCAB ? v : (VOCAB - 1));
    if constexpr (PRE)
      bbase[nt] = (const char*)((const unsigned short*)W + vc * 256);
    else
      bbase[nt] = (const char*)((const float*)W + vc * 256);
  }

  for (int kc = 0; kc < 8; ++kc) {
    const int k0 = kc * 32 + quad * 8;           // bf16 element index
    bf16x8 af[4], bfr[4];
    #pragma unroll
    for (int mt = 0; mt < 4; ++mt) {
      int row = mt * 16 + lm;
      uint32_t byte = (uint32_t)(row << 9) + (uint32_t)(k0 << 1);
      byte ^= (uint32_t)((row & 7) << 4);
      af[mt] = *(const bf16x8*)((const char*)Alds + byte);
    }
    #pragma unroll
    for (int nt = 0; nt < 4; ++nt) {
      if constexpr (PRE) {
        bfr[nt] = *(const bf16x8*)(bbase[nt] + (size_t)k0 * 2);
      } else {
        const float* bp = (const float*)bbase[nt];
        f32x4 w0 = *(const f32x4*)&bp[k0];
        f32x4 w1 = *(const f32x4*)&bp[k0 + 4];
        bf16x8 b;
        b[0] = (short)f2bf(w0.x); b[1] = (short)f2bf(w0.y);
        b[2] = (short)f2bf(w0.z); b[3] = (short)f2bf(w0.w);
        b[4] = (short)f2bf(w1.x); b[5] = (short)f2bf(w1.y);
        b[6] = (short)f2bf(w1.z); b[7] = (short)f2bf(w1.w);
        bfr[nt] = b;
      }
    }
    #pragma unroll
    for (int mt = 0; mt < 4; ++mt)
      #pragma unroll
      for (int nt = 0; nt < 4; ++nt)
        acc[mt][nt] = __builtin_amdgcn_mfma_f32_16x16x32_bf16(
            af[mt], bfr[nt], acc[mt][nt], 0, 0, 0);
  }

  #pragma unroll
  for (int nt = 0; nt < 4; ++nt) {
    int v = vbase + nt * 16 + lm;
    if (v >= VOCAB) continue;
    float bias = bfc[v];
    #pragma unroll
    for (int mt = 0; mt < 4; ++mt) {
      int row = m0 + mt * 16 + quad * 4;
      #pragma unroll
      for (int r = 0; r < 4; ++r)
        out[(size_t)(row + r) * VOCAB + v] = acc[mt][nt][r] + bias;
    }
  }
}

// ---------------------------------------------------------------------------
extern "C" void kernel_launch(void* const* d_in, const int* in_sizes, int n_in,
                              void* d_out, int out_size, void* d_ws, size_t ws_size,
                              hipStream_t stream) {
  const int*   x     = (const int*)d_in[0];
  const float* t     = (const float*)d_in[1];
  const float* s     = (const float*)d_in[2];
  // d_in[3] = y_t, d_in[4] = y_s  (unused by reference)
  const float* h0    = (const float*)d_in[5];
  const int*   au    = (const int*)d_in[6];
  const int*   len   = (const int*)d_in[7];
  const float* Wenc  = (const float*)d_in[8];
  const float* Wuser = (const float*)d_in[9];
  const float* Wih   = (const float*)d_in[10];
  const float* Whh   = (const float*)d_in[11];
  const float* bih   = (const float*)d_in[12];
  const float* bhh   = (const float*)d_in[13];
  const float* Wfc   = (const float*)d_in[14];
  const float* bfc   = (const float*)d_in[15];
  float* out = (float*)d_out;

  char* ws = (char*)d_ws;
  float*          E    = (float*)(ws);                    // 100000*128*4 = 51,200,000
  float*          wbuf = (float*)(ws + 51200000);         // 200*1024*4   =    819,200
  unsigned short* Ab   = (unsigned short*)(ws + 52019200);// 1024*256*2   =    524,288
  unsigned short* Wfcb = (unsigned short*)(ws + 52543488);// 100000*256*2 = 51,200,000
  const size_t need = 52543488ull + 51200000ull;          // 103,743,488
  const bool pre = ws_size >= need;

  if (pre) k0_wfc_bf16<<<12500, 256, 0, stream>>>(Wfc, Wfcb);
  k1_eprecomp<<<1563, 256, 0, stream>>>(Wenc, Wih, bih, bhh, E);
  k1b_weights<<<800, 256, 0, stream>>>(t, s, len, wbuf);
  k2_rnn<<<1024, 256, 0, stream>>>(x, E, Whh, h0, wbuf, au, Wuser, Ab);
  if (pre)
    k3_gemm<true><<<6256, 256, 0, stream>>>(Ab, (const void*)Wfcb, bfc, out);
  else
    k3_gemm<false><<<6256, 256, 0, stream>>>(Ab, (const void*)Wfc, bfc, out);
}